// Round 23
// baseline (82.448 us; speedup 1.0000x reference)
//
#include <hip/hip_runtime.h>

#define N2 8192
#define NHALF 4096
#define DDIM 128
#define NCHUNK 16
#define CPC 512           // cols per chunk
#define NT 8              // B-tiles per chunk (512/64)
#define LN2F 0.69314718055994530942f
// SCALEF = sqrt(log2(e)/T) with T=0.5 -> sqrt(2.8853900817779268)
#define SCALEF 1.6986436f
#define FXSCALE 1073741824.0   // 2^30 fixed-point for deterministic atomics

typedef __attribute__((ext_vector_type(8))) short bf8_t;   // 8 bf16 = 4 VGPR
typedef __attribute__((ext_vector_type(4))) float f4_t;    // MFMA C/D frag

__device__ __forceinline__ float fexp2(float x) { return __builtin_amdgcn_exp2f(x); }
__device__ __forceinline__ float flog2(float x) { return __builtin_amdgcn_logf(x); }

__device__ __forceinline__ unsigned short f2bf(float f) {
  unsigned int x = __float_as_uint(f);
  x += 0x7fffu + ((x >> 16) & 1u);   // RNE (no NaN inputs here)
  return (unsigned short)(x >> 16);
}
__device__ __forceinline__ float bf2f(unsigned short h) {
  return __uint_as_float(((unsigned int)h) << 16);
}

// ---------------------------------------------------------------------------
// Kernel 1: normalize rows -> bf16 u, dhat; ALSO resets the krow accumulator
// and ticket (graph-replay safe: runs every call, before krow).
// ---------------------------------------------------------------------------
__global__ __launch_bounds__(256) void knorm(const float* __restrict__ zi,
                                             const float* __restrict__ zj,
                                             unsigned short* __restrict__ u,
                                             float* __restrict__ dhat,
                                             unsigned long long* __restrict__ acc,
                                             unsigned int* __restrict__ ticket) {
  if (blockIdx.x == 0 && threadIdx.x == 0) { acc[0] = 0ull; ticket[0] = 0u; }
  const int lane = threadIdx.x & 63;
  const int row = blockIdx.x * 4 + (threadIdx.x >> 6);
  const float* src = (row < NHALF) ? (zi + (size_t)row * DDIM)
                                   : (zj + (size_t)(row - NHALF) * DDIM);
  float2 x = *(const float2*)(src + lane * 2);
  float ss = x.x * x.x + x.y * x.y;
#pragma unroll
  for (int m = 32; m; m >>= 1) ss += __shfl_xor(ss, m);
  float scale = SCALEF / fmaxf(sqrtf(ss), 1e-8f);  // eps clamp as in reference
  unsigned short b0 = f2bf(x.x * scale);
  unsigned short b1 = f2bf(x.y * scale);
  *(unsigned int*)(u + (size_t)row * DDIM + lane * 2) =
      (unsigned int)b0 | ((unsigned int)b1 << 16);
  float f0 = bf2f(b0), f1 = bf2f(b1);
  float dd = f0 * f0 + f1 * f1;
#pragma unroll
  for (int m = 32; m; m >>= 1) dd += __shfl_xor(dd, m);
  if (lane == 0) dhat[row] = dd;
}

// ---------------------------------------------------------------------------
// Kernel 2: fused sim GEMM + per-row sum of exp2 (r18 chassis, best measured
// ksim ~25.5us). r22 change: A is no longer GATHERED (64 instrs x 16 line
// segments each, all WGs at t=0 -> ~3-4us TA serialization); instead the
// WG's 256 rows (64KB CONTIGUOUS in u) are staged by 64 linear 1KB DMAs
// (involution pre-swizzle: unit d of row r stored at d^(r&7)), fragments
// extracted by swizzled ds_read (same XOR), pinned; then the proven B
// pipeline runs in the first 48KB (A region reused as the 3-buf ring).
// B path unchanged (validated r11-r18): lane-contiguous 1KB global_load_lds,
// depth-2 prefetch, loop-top vmcnt(2), ONE s_barrier/tile, vmcnt(0) only at
// last tile. 8 waves x 32 rows, lean a[2][4]. LDS 64KB -> 2 WG/CU.
// Lp layout [row][16] (chunk minor) for krow's 1-line partial read.
// ---------------------------------------------------------------------------
__global__ __launch_bounds__(512) void ksim(const unsigned short* __restrict__ u,
                                            float* __restrict__ Lp) {
  __shared__ short Bls[32768];  // 64KB: A-stage; first 48KB reused as B-ring
  const int tid = threadIdx.x;
  const int lane = tid & 63;
  const int w = tid >> 6;                  // 0..7
  const int rb = blockIdx.x >> 4;          // 0..31
  const int chunk = blockIdx.x & 15;       // 0..15
  const int lr = lane & 15, lq = lane >> 4;
  const int rowbase = rb * 256;            // WG's 256 rows (64KB contiguous)
  const int colbase = chunk * CPC;

  // ---- A stage: 64 linear 1KB DMAs (8 per wave), involution pre-swizzle.
  // DMA k covers LDS units [k*64,(k+1)*64): rows k*4+lq, stored unit
  // d = lr ^ ((4k+lq)&7) = lr ^ (4*(k&1)+lq).
#pragma unroll
  for (int i = 0; i < 8; i++) {
    const int k = w * 8 + i;
    const int row_local = k * 4 + lq;
    const int sdu = lr ^ (4 * (k & 1) + lq);
    const unsigned short* src =
        u + (size_t)(rowbase + row_local) * DDIM + sdu * 8;
    short* dst = &Bls[k * 512];            // wave-uniform, linear
    __builtin_amdgcn_global_load_lds(
        (const __attribute__((address_space(1))) unsigned int*)src,
        (__attribute__((address_space(3))) unsigned int*)dst, 16, 0, 0);
  }
  asm volatile("s_waitcnt vmcnt(0)" ::: "memory");
  __builtin_amdgcn_sched_barrier(0);
  __builtin_amdgcn_s_barrier();            // A staged
  __builtin_amdgcn_sched_barrier(0);

  // ---- A extract (swizzled ds_read): R = w*32+s*16+lr; unit kc*4+lq at
  // LDS slot (kc*4+lq)^(R&7) = (kc*4+lq)^(lr&7) since w*32,s*16 = 0 mod 8.
  bf8_t a[2][4];
#pragma unroll
  for (int s = 0; s < 2; s++)
#pragma unroll
    for (int kc = 0; kc < 4; kc++) {
      const int R = w * 32 + s * 16 + lr;
      a[s][kc] = *(const bf8_t*)&Bls[(R * 16 + ((kc * 4 + lq) ^ (lr & 7))) * 8];
    }
#pragma unroll
  for (int s = 0; s < 2; s++)
#pragma unroll
    for (int kc = 0; kc < 4; kc++)
      asm volatile("" : "+v"(a[s][kc]));   // materialize (lgkm drained)
  __builtin_amdgcn_sched_barrier(0);
  __builtin_amdgcn_s_barrier();            // all extracts done before ring use
  __builtin_amdgcn_sched_barrier(0);

  f4_t L0 = {0.f, 0.f, 0.f, 0.f}, L1 = {0.f, 0.f, 0.f, 0.f};

  // ---- B stage: 64-col tile = 16KB = 16 linear 1KB DMAs (2 per wave).
  auto STAGE = [&](int t) {
#pragma unroll
    for (int i = 0; i < 2; i++) {
      const int j = w * 2 + i;
      const int col_local = j * 4 + lq;
      const int sdu = lr ^ (4 * (j & 1) + lq);
      const unsigned short* src =
          u + (size_t)(colbase + t * 64 + col_local) * DDIM + sdu * 8;
      short* dst = &Bls[(t % 3) * 8192 + j * 512];
      __builtin_amdgcn_global_load_lds(
          (const __attribute__((address_space(1))) unsigned int*)src,
          (__attribute__((address_space(3))) unsigned int*)dst, 16, 0, 0);
    }
  };

  auto COMP = [&](int t) {
    const short* P = &Bls[(t % 3) * 8192];
#pragma unroll
    for (int g = 0; g < 4; g++) {
      bf8_t bv[4];
#pragma unroll
      for (int kc = 0; kc < 4; kc++)
        bv[kc] = *(const bf8_t*)&P[((g * 16 + lr) * 16 +
                                    ((kc * 4 + lq) ^ (lr & 7))) * 8];
      f4_t acc0 = {0.f, 0.f, 0.f, 0.f}, acc1 = {0.f, 0.f, 0.f, 0.f};
#pragma unroll
      for (int kc = 0; kc < 4; kc++) {
        acc0 = __builtin_amdgcn_mfma_f32_16x16x32_bf16(a[0][kc], bv[kc], acc0, 0, 0, 0);
        acc1 = __builtin_amdgcn_mfma_f32_16x16x32_bf16(a[1][kc], bv[kc], acc1, 0, 0, 0);
      }
#pragma unroll
      for (int r = 0; r < 4; r++) {
        L0[r] += fexp2(acc0[r]);
        L1[r] += fexp2(acc1[r]);
      }
    }
  };

  // depth-2 prefetch, 1 barrier/tile, counted vmcnt (never 0 until the end)
  STAGE(0);
  STAGE(1);
#pragma unroll 1
  for (int t = 0; t < NT; ++t) {
    if (t < NT - 1) {
      asm volatile("s_waitcnt vmcnt(2)" ::: "memory");   // my tile-t DMAs done
    } else {
      asm volatile("s_waitcnt vmcnt(0)" ::: "memory");
    }
    __builtin_amdgcn_sched_barrier(0);
    __builtin_amdgcn_s_barrier();                        // all waves' tile-t done
    __builtin_amdgcn_sched_barrier(0);
    COMP(t);
    if (t + 2 < NT) STAGE(t + 2);
  }

  // reduce across the 16 column-lanes; Lp layout [row][16] (chunk minor)
#pragma unroll
  for (int r = 0; r < 4; r++) {
    float v0 = L0[r], v1 = L1[r];
    v0 += __shfl_xor(v0, 1); v0 += __shfl_xor(v0, 2);
    v0 += __shfl_xor(v0, 4); v0 += __shfl_xor(v0, 8);
    v1 += __shfl_xor(v1, 1); v1 += __shfl_xor(v1, 2);
    v1 += __shfl_xor(v1, 4); v1 += __shfl_xor(v1, 8);
    if (lr == 0) {
      const int rrow = rowbase + w * 32 + lq * 4 + r;
      Lp[(size_t)rrow * NCHUNK + chunk] = v0;          // rows 0-15 of strip
      Lp[(size_t)(rrow + 16) * NCHUNK + chunk] = v1;   // rows 16-31
    }
  }
}

// ---------------------------------------------------------------------------
// Kernel 3: per-row loss + FUSED final mean (saves the kfinal launch).
// Wave-per-row (validated r19): lane-parallel dot + shuffle reduce. Block
// partial is added to a u64 fixed-point accumulator (integer adds are
// order-independent -> deterministic); ticket-counted last block converts
// and writes out[0]. acc/ticket reset by knorm each call (replay-safe).
// ---------------------------------------------------------------------------
__global__ __launch_bounds__(256) void krow(const unsigned short* __restrict__ u,
                                            const float* __restrict__ dhat,
                                            const float* __restrict__ Lp,
                                            unsigned long long* __restrict__ acc,
                                            unsigned int* __restrict__ ticket,
                                            float* __restrict__ out) {
  const int lane = threadIdx.x & 63;
  const int w = threadIdx.x >> 6;
  const int i = blockIdx.x * 4 + w;
  const int j = (i + NHALF) & (N2 - 1);  // positive-pair label

  const unsigned int av = ((const unsigned int*)(u + (size_t)i * DDIM))[lane];
  const unsigned int bv = ((const unsigned int*)(u + (size_t)j * DDIM))[lane];
  float dot = __uint_as_float(av << 16) * __uint_as_float(bv << 16) +
              __uint_as_float(av & 0xffff0000u) * __uint_as_float(bv & 0xffff0000u);
  float ls = (lane < NCHUNK) ? Lp[(size_t)i * NCHUNK + lane] : 0.f;
#pragma unroll
  for (int m = 32; m; m >>= 1) {
    dot += __shfl_xor(dot, m);
    ls += __shfl_xor(ls, m);
  }
  __shared__ float sred[4];
  if (lane == 0) {
    const float L = ls - fexp2(dhat[i]);   // remove self-similarity term
    sred[w] = LN2F * (flog2(L) - dot);
  }
  __syncthreads();
  if (threadIdx.x == 0) {
    const float part = sred[0] + sred[1] + sred[2] + sred[3];  // >0 always
    const unsigned long long q =
        (unsigned long long)((double)part * FXSCALE + 0.5);
    atomicAdd(acc, q);
    __threadfence();                        // order acc-add before ticket-add
    const unsigned int old = atomicAdd(ticket, 1u);
    if (old == (unsigned int)(N2 / 4 - 1)) {
      const unsigned long long tot = atomicAdd(acc, 0ull);  // total-order read
      out[0] = (float)((double)tot * (1.0 / FXSCALE) * (1.0 / N2));
    }
  }
}

// ---------------------------------------------------------------------------
// ws layout: u bf16 [8192][128] (2 MB) | dhat f32[8192] (32 KB) |
//            Lp f32[8192][16] (512 KB) | acc u64 | ticket u32  -> ~2.6 MB
// ---------------------------------------------------------------------------
extern "C" void kernel_launch(void* const* d_in, const int* in_sizes, int n_in,
                              void* d_out, int out_size, void* d_ws, size_t ws_size,
                              hipStream_t stream) {
  const float* zi = (const float*)d_in[0];
  const float* zj = (const float*)d_in[1];
  char* ws = (char*)d_ws;
  unsigned short* u = (unsigned short*)ws;
  float* dhat = (float*)(ws + (size_t)N2 * DDIM * 2);
  float* Lp = (float*)(ws + (size_t)N2 * DDIM * 2 + (size_t)N2 * 4);
  unsigned long long* acc =
      (unsigned long long*)(ws + (size_t)N2 * DDIM * 2 + (size_t)N2 * 4 +
                            (size_t)NCHUNK * N2 * 4);
  unsigned int* ticket = (unsigned int*)(acc + 1);
  float* out = (float*)d_out;

  hipLaunchKernelGGL(knorm, dim3(N2 / 4), dim3(256), 0, stream, zi, zj, u, dhat,
                     acc, ticket);
  hipLaunchKernelGGL(ksim, dim3((N2 / 256) * NCHUNK), dim3(512), 0, stream, u, Lp);
  hipLaunchKernelGGL(krow, dim3(N2 / 4), dim3(256), 0, stream, u, dhat, Lp,
                     acc, ticket, out);
}

// Round 24
// 34.656 us; speedup vs baseline: 2.3790x; 2.3790x over previous
//
#include <hip/hip_runtime.h>

#define N2 8192
#define NHALF 4096
#define DDIM 128
#define NCHUNK 16
#define CPC 512           // cols per chunk
#define NT 8              // B-tiles per chunk (512/64)
#define LN2F 0.69314718055994530942f
// SCALEF = sqrt(log2(e)/T) with T=0.5 -> sqrt(2.8853900817779268)
#define SCALEF 1.6986436f

typedef __attribute__((ext_vector_type(8))) short bf8_t;   // 8 bf16 = 4 VGPR
typedef __attribute__((ext_vector_type(4))) float f4_t;    // MFMA C/D frag

__device__ __forceinline__ float fexp2(float x) { return __builtin_amdgcn_exp2f(x); }
__device__ __forceinline__ float flog2(float x) { return __builtin_amdgcn_logf(x); }

__device__ __forceinline__ unsigned short f2bf(float f) {
  unsigned int x = __float_as_uint(f);
  x += 0x7fffu + ((x >> 16) & 1u);   // RNE (no NaN inputs here)
  return (unsigned short)(x >> 16);
}
__device__ __forceinline__ float bf2f(unsigned short h) {
  return __uint_as_float(((unsigned int)h) << 16);
}

// ---------------------------------------------------------------------------
// Kernel 1: normalize rows, scale by sqrt(log2e/T), store bf16 u[8192][128];
// also store dhat[i] = sum_k u_bf16[i][k]^2 (diag logit). Unchanged (passing).
// ---------------------------------------------------------------------------
__global__ __launch_bounds__(256) void knorm(const float* __restrict__ zi,
                                             const float* __restrict__ zj,
                                             unsigned short* __restrict__ u,
                                             float* __restrict__ dhat) {
  const int lane = threadIdx.x & 63;
  const int row = blockIdx.x * 4 + (threadIdx.x >> 6);
  const float* src = (row < NHALF) ? (zi + (size_t)row * DDIM)
                                   : (zj + (size_t)(row - NHALF) * DDIM);
  float2 x = *(const float2*)(src + lane * 2);
  float ss = x.x * x.x + x.y * x.y;
#pragma unroll
  for (int m = 32; m; m >>= 1) ss += __shfl_xor(ss, m);
  float scale = SCALEF / fmaxf(sqrtf(ss), 1e-8f);  // eps clamp as in reference
  unsigned short b0 = f2bf(x.x * scale);
  unsigned short b1 = f2bf(x.y * scale);
  *(unsigned int*)(u + (size_t)row * DDIM + lane * 2) =
      (unsigned int)b0 | ((unsigned int)b1 << 16);
  float f0 = bf2f(b0), f1 = bf2f(b1);
  float dd = f0 * f0 + f1 * f1;
#pragma unroll
  for (int m = 32; m; m >>= 1) dd += __shfl_xor(dd, m);
  if (lane == 0) dhat[row] = dd;
}

// ---------------------------------------------------------------------------
// Kernel 2: fused sim GEMM + per-row sum of exp2 (r23 ksim, MEASURED ~20us:
// linear A-stage removed the gathered-A TA tax, ~5us win vs r18's 25.5).
// A: WG's 256 rows (64KB contiguous) staged by 64 linear 1KB DMAs
// (involution pre-swizzle: unit d of row r stored at d^(r&7)); frags
// extracted by swizzled ds_read (same XOR), pinned; A region then reused
// as the 3-buf B ring. B path validated r11-r18: lane-contiguous 1KB
// global_load_lds, depth-2 prefetch, loop-top vmcnt(2), ONE s_barrier/tile,
// vmcnt(0) only at last tile. 8 waves x 32 rows, lean a[2][4]. LDS 64KB.
// Lp layout [row][16] (chunk minor) for krow's 1-line partial read.
// ---------------------------------------------------------------------------
__global__ __launch_bounds__(512) void ksim(const unsigned short* __restrict__ u,
                                            float* __restrict__ Lp) {
  __shared__ short Bls[32768];  // 64KB: A-stage; first 48KB reused as B-ring
  const int tid = threadIdx.x;
  const int lane = tid & 63;
  const int w = tid >> 6;                  // 0..7
  const int rb = blockIdx.x >> 4;          // 0..31
  const int chunk = blockIdx.x & 15;       // 0..15
  const int lr = lane & 15, lq = lane >> 4;
  const int rowbase = rb * 256;            // WG's 256 rows (64KB contiguous)
  const int colbase = chunk * CPC;

  // ---- A stage: 64 linear 1KB DMAs (8 per wave), involution pre-swizzle.
#pragma unroll
  for (int i = 0; i < 8; i++) {
    const int k = w * 8 + i;
    const int row_local = k * 4 + lq;
    const int sdu = lr ^ (4 * (k & 1) + lq);
    const unsigned short* src =
        u + (size_t)(rowbase + row_local) * DDIM + sdu * 8;
    short* dst = &Bls[k * 512];            // wave-uniform, linear
    __builtin_amdgcn_global_load_lds(
        (const __attribute__((address_space(1))) unsigned int*)src,
        (__attribute__((address_space(3))) unsigned int*)dst, 16, 0, 0);
  }
  asm volatile("s_waitcnt vmcnt(0)" ::: "memory");
  __builtin_amdgcn_sched_barrier(0);
  __builtin_amdgcn_s_barrier();            // A staged
  __builtin_amdgcn_sched_barrier(0);

  // ---- A extract (swizzled ds_read): R = w*32+s*16+lr; unit kc*4+lq at
  // LDS slot (kc*4+lq)^(R&7) = (kc*4+lq)^(lr&7) since w*32,s*16 = 0 mod 8.
  bf8_t a[2][4];
#pragma unroll
  for (int s = 0; s < 2; s++)
#pragma unroll
    for (int kc = 0; kc < 4; kc++) {
      const int R = w * 32 + s * 16 + lr;
      a[s][kc] = *(const bf8_t*)&Bls[(R * 16 + ((kc * 4 + lq) ^ (lr & 7))) * 8];
    }
#pragma unroll
  for (int s = 0; s < 2; s++)
#pragma unroll
    for (int kc = 0; kc < 4; kc++)
      asm volatile("" : "+v"(a[s][kc]));   // materialize (lgkm drained)
  __builtin_amdgcn_sched_barrier(0);
  __builtin_amdgcn_s_barrier();            // all extracts done before ring use
  __builtin_amdgcn_sched_barrier(0);

  f4_t L0 = {0.f, 0.f, 0.f, 0.f}, L1 = {0.f, 0.f, 0.f, 0.f};

  // ---- B stage: 64-col tile = 16KB = 16 linear 1KB DMAs (2 per wave).
  auto STAGE = [&](int t) {
#pragma unroll
    for (int i = 0; i < 2; i++) {
      const int j = w * 2 + i;
      const int col_local = j * 4 + lq;
      const int sdu = lr ^ (4 * (j & 1) + lq);
      const unsigned short* src =
          u + (size_t)(colbase + t * 64 + col_local) * DDIM + sdu * 8;
      short* dst = &Bls[(t % 3) * 8192 + j * 512];
      __builtin_amdgcn_global_load_lds(
          (const __attribute__((address_space(1))) unsigned int*)src,
          (__attribute__((address_space(3))) unsigned int*)dst, 16, 0, 0);
    }
  };

  auto COMP = [&](int t) {
    const short* P = &Bls[(t % 3) * 8192];
#pragma unroll
    for (int g = 0; g < 4; g++) {
      bf8_t bv[4];
#pragma unroll
      for (int kc = 0; kc < 4; kc++)
        bv[kc] = *(const bf8_t*)&P[((g * 16 + lr) * 16 +
                                    ((kc * 4 + lq) ^ (lr & 7))) * 8];
      f4_t acc0 = {0.f, 0.f, 0.f, 0.f}, acc1 = {0.f, 0.f, 0.f, 0.f};
#pragma unroll
      for (int kc = 0; kc < 4; kc++) {
        acc0 = __builtin_amdgcn_mfma_f32_16x16x32_bf16(a[0][kc], bv[kc], acc0, 0, 0, 0);
        acc1 = __builtin_amdgcn_mfma_f32_16x16x32_bf16(a[1][kc], bv[kc], acc1, 0, 0, 0);
      }
#pragma unroll
      for (int r = 0; r < 4; r++) {
        L0[r] += fexp2(acc0[r]);
        L1[r] += fexp2(acc1[r]);
      }
    }
  };

  // depth-2 prefetch, 1 barrier/tile, counted vmcnt (never 0 until the end)
  STAGE(0);
  STAGE(1);
#pragma unroll 1
  for (int t = 0; t < NT; ++t) {
    if (t < NT - 1) {
      asm volatile("s_waitcnt vmcnt(2)" ::: "memory");   // my tile-t DMAs done
    } else {
      asm volatile("s_waitcnt vmcnt(0)" ::: "memory");
    }
    __builtin_amdgcn_sched_barrier(0);
    __builtin_amdgcn_s_barrier();                        // all waves' tile-t done
    __builtin_amdgcn_sched_barrier(0);
    COMP(t);
    if (t + 2 < NT) STAGE(t + 2);
  }

  // reduce across the 16 column-lanes; Lp layout [row][16] (chunk minor)
#pragma unroll
  for (int r = 0; r < 4; r++) {
    float v0 = L0[r], v1 = L1[r];
    v0 += __shfl_xor(v0, 1); v0 += __shfl_xor(v0, 2);
    v0 += __shfl_xor(v0, 4); v0 += __shfl_xor(v0, 8);
    v1 += __shfl_xor(v1, 1); v1 += __shfl_xor(v1, 2);
    v1 += __shfl_xor(v1, 4); v1 += __shfl_xor(v1, 8);
    if (lr == 0) {
      const int rrow = rowbase + w * 32 + lq * 4 + r;
      Lp[(size_t)rrow * NCHUNK + chunk] = v0;          // rows 0-15 of strip
      Lp[(size_t)(rrow + 16) * NCHUNK + chunk] = v1;   // rows 16-31
    }
  }
}

// ---------------------------------------------------------------------------
// Kernel 3: per-row loss, wave-per-row (r19, measured fast): lane-parallel
// dot + shuffle reduce; Lp partials read as one 64B line. NO global atomics
// (r23 lesson: 2048 same-line device atomics = 54us). grid = 2048 x 256.
// ---------------------------------------------------------------------------
__global__ __launch_bounds__(256) void krow(const unsigned short* __restrict__ u,
                                            const float* __restrict__ dhat,
                                            const float* __restrict__ Lp,
                                            float* __restrict__ bsum) {
  const int lane = threadIdx.x & 63;
  const int w = threadIdx.x >> 6;
  const int i = blockIdx.x * 4 + w;
  const int j = (i + NHALF) & (N2 - 1);  // positive-pair label

  const unsigned int av = ((const unsigned int*)(u + (size_t)i * DDIM))[lane];
  const unsigned int bv = ((const unsigned int*)(u + (size_t)j * DDIM))[lane];
  float dot = __uint_as_float(av << 16) * __uint_as_float(bv << 16) +
              __uint_as_float(av & 0xffff0000u) * __uint_as_float(bv & 0xffff0000u);
  float ls = (lane < NCHUNK) ? Lp[(size_t)i * NCHUNK + lane] : 0.f;
#pragma unroll
  for (int m = 32; m; m >>= 1) {
    dot += __shfl_xor(dot, m);
    ls += __shfl_xor(ls, m);
  }
  __shared__ float sred[4];
  if (lane == 0) {
    const float L = ls - fexp2(dhat[i]);   // remove self-similarity term
    sred[w] = LN2F * (flog2(L) - dot);
  }
  __syncthreads();
  if (threadIdx.x == 0)
    bsum[blockIdx.x] = sred[0] + sred[1] + sred[2] + sred[3];
}

// ---------------------------------------------------------------------------
// Kernel 4: final mean over the 2048 block partials (fixed-order, determin.).
// ---------------------------------------------------------------------------
__global__ void kfinal(const float* __restrict__ bsum, float* __restrict__ out) {
  float v = 0.f;
#pragma unroll
  for (int jj = 0; jj < 32; jj++) v += bsum[threadIdx.x + 64 * jj];
#pragma unroll
  for (int m = 32; m; m >>= 1) v += __shfl_xor(v, m);
  if (threadIdx.x == 0) out[0] = v * (1.0f / N2);
}

// ---------------------------------------------------------------------------
// ws layout: u bf16 [8192][128] (2 MB) | dhat f32[8192] (32 KB) |
//            Lp f32[8192][16] (512 KB) | bsum f32[2048] (8 KB)  -> ~2.6 MB
// ---------------------------------------------------------------------------
extern "C" void kernel_launch(void* const* d_in, const int* in_sizes, int n_in,
                              void* d_out, int out_size, void* d_ws, size_t ws_size,
                              hipStream_t stream) {
  const float* zi = (const float*)d_in[0];
  const float* zj = (const float*)d_in[1];
  char* ws = (char*)d_ws;
  unsigned short* u = (unsigned short*)ws;
  float* dhat = (float*)(ws + (size_t)N2 * DDIM * 2);
  float* Lp = (float*)(ws + (size_t)N2 * DDIM * 2 + (size_t)N2 * 4);
  float* bsum = (float*)(ws + (size_t)N2 * DDIM * 2 + (size_t)N2 * 4 +
                         (size_t)NCHUNK * N2 * 4);
  float* out = (float*)d_out;

  hipLaunchKernelGGL(knorm, dim3(N2 / 4), dim3(256), 0, stream, zi, zj, u, dhat);
  hipLaunchKernelGGL(ksim, dim3((N2 / 256) * NCHUNK), dim3(512), 0, stream, u, Lp);
  hipLaunchKernelGGL(krow, dim3(N2 / 4), dim3(256), 0, stream, u, dhat, Lp, bsum);
  hipLaunchKernelGGL(kfinal, dim3(1), dim3(64), 0, stream, bsum, out);
}